// Round 9
// baseline (75211.633 us; speedup 1.0000x reference)
//
#include <hip/hip_runtime.h>

typedef unsigned short u16;
typedef unsigned int   u32;
typedef long long      i64;
typedef __attribute__((ext_vector_type(8))) short short8;

#define W_N   2048
#define C_N   24
#define E_N   512
#define H_N   1024
#define G3_N  3072
#define CH    256      // phase-1 word chunk
#define SEG   512      // phase-2 word segment

#define MD_BF16 0u
#define MD_F32  1u
#define MD_ZERO 2u

__device__ inline float bf2f(u16 u) { union { u32 i; float f; } v; v.i = ((u32)u) << 16; return v.f; }
__device__ inline u16 f2bf(float f) {
  union { float f; u32 i; } v; v.f = f;
  u32 i = v.i;
  u32 r = (i + 0x7fffu + ((i >> 16) & 1u)) >> 16;
  return (u16)r;
}
__device__ inline float ld1(const void* p, size_t eoff, u32 md) {
  if (md == MD_F32) return ((const float*)p)[eoff];
  if (md == MD_ZERO) return 0.f;
  return bf2f(((const u16*)p)[eoff]);
}
__device__ inline short8 ld8(const void* p, size_t eoff, u32 md) {
  short8 r;
  if (md == MD_BF16) return *(const short8*)((const u16*)p + eoff);
  if (md == MD_ZERO) {
#pragma unroll
    for (int i = 0; i < 8; ++i) r[i] = 0;
    return r;
  }
  const float* f = (const float*)p + eoff;
#pragma unroll
  for (int i = 0; i < 8; ++i) r[i] = (short)f2bf(f[i]);
  return r;
}

__global__ void sniff_kernel(const u16* __restrict__ t, u32* __restrict__ flag) {
  if (threadIdx.x == 0 && blockIdx.x == 0) {
    int cnt = 0, nz = 0;
    for (int i = 0; i < 512; ++i) {
      u32 v = t[i];
      if (v != 0u) nz++;
      u32 e = (v >> 7) & 0xffu;
      if (e >= 100u && e <= 130u) cnt++;
    }
    *flag = (nz == 0) ? MD_ZERO : ((cnt >= 440) ? MD_BF16 : MD_F32);
  }
}

__global__ void sniffx_kernel(const int* __restrict__ xi, u32* __restrict__ flag) {
  if (threadIdx.x == 0 && blockIdx.x == 0) {
    int oddzero = 0;
    for (int i = 0; i < 128; ++i)
      if (xi[2 * i + 1] == 0) oddzero++;
    *flag = (oddzero >= 120) ? 1u : 0u;   // 1 => int64
  }
}

// ---- Naive tiled GEMM, fp32 out ----
// Cout(local M x 3072) = A[m_base+m] @ Wt^T + bias ; 32x32 tile, 16x16 thr.
template<int GATHER>
__global__ __launch_bounds__(256)
void ngemm_kernel(const void* __restrict__ A, const void* __restrict__ Wt,
                  const void* __restrict__ bias, float* __restrict__ Cout,
                  const void* __restrict__ X, int xoff, int gstride, int K,
                  const u32* __restrict__ flags, int afi, int wfi, int bfi,
                  int m_base) {
  __shared__ float As[32][17];
  __shared__ float Bs[32][17];
  const u32 am = (afi == -1) ? MD_BF16 : ((afi == -2) ? MD_F32 : flags[afi]);
  const u32 wm = flags[wfi];
  const u32 bm = flags[bfi];
  const int tx = threadIdx.x, ty = threadIdx.y;
  const int lrow0 = blockIdx.y * 32 + ty;
  const int lrow1 = lrow0 + 16;
  const int col0 = blockIdx.x * 32 + tx;
  const int col1 = col0 + 16;
  int arow0 = m_base + lrow0, arow1 = m_base + lrow1;
  if (GATHER) {
    if (flags[0]) {
      arow0 = (int)((const i64*)X)[(size_t)arow0 * gstride + xoff];
      arow1 = (int)((const i64*)X)[(size_t)arow1 * gstride + xoff];
    } else {
      arow0 = ((const int*)X)[(size_t)arow0 * gstride + xoff];
      arow1 = ((const int*)X)[(size_t)arow1 * gstride + xoff];
    }
    arow0 = min(max(arow0, 0), 100);
    arow1 = min(max(arow1, 0), 100);
  }
  float a00 = 0.f, a01 = 0.f, a10 = 0.f, a11 = 0.f;
  for (int k0 = 0; k0 < K; k0 += 16) {
    As[ty][tx]      = ld1(A, (size_t)arow0 * K + k0 + tx, am);
    As[ty + 16][tx] = ld1(A, (size_t)arow1 * K + k0 + tx, am);
    Bs[ty][tx]      = ld1(Wt, (size_t)(blockIdx.x * 32 + ty) * K + k0 + tx, wm);
    Bs[ty + 16][tx] = ld1(Wt, (size_t)(blockIdx.x * 32 + ty + 16) * K + k0 + tx, wm);
    __syncthreads();
#pragma unroll
    for (int kk = 0; kk < 16; ++kk) {
      const float av0 = As[ty][kk], av1 = As[ty + 16][kk];
      const float bv0 = Bs[tx][kk], bv1 = Bs[tx + 16][kk];
      a00 = fmaf(av0, bv0, a00);
      a01 = fmaf(av0, bv1, a01);
      a10 = fmaf(av1, bv0, a10);
      a11 = fmaf(av1, bv1, a11);
    }
    __syncthreads();
  }
  const float b0 = ld1(bias, col0, bm);
  const float b1 = ld1(bias, col1, bm);
  Cout[(size_t)lrow0 * G3_N + col0] = a00 + b0;
  Cout[(size_t)lrow0 * G3_N + col1] = a01 + b1;
  Cout[(size_t)lrow1 * G3_N + col0] = a10 + b0;
  Cout[(size_t)lrow1 * G3_N + col1] = a11 + b1;
}

__global__ __launch_bounds__(256)
void gru_cell_kernel(const float* __restrict__ gi, const float* __restrict__ gh,
                     float* __restrict__ hf, float* __restrict__ wout, int mb) {
  const int idx = blockIdx.x * 256 + threadIdx.x;   // CH*1024 threads
  const int m = idx >> 10, j = idx & 1023;
  const float* gim = gi + (size_t)m * G3_N;
  const float* ghm = gh + (size_t)m * G3_N;
  const float ir = gim[j], iz = gim[1024 + j], inn = gim[2048 + j];
  const float hr = ghm[j], hz = ghm[1024 + j], hn = ghm[2048 + j];
  const float r = 1.f / (1.f + expf(-(ir + hr)));
  const float z = 1.f / (1.f + expf(-(iz + hz)));
  const float n = tanhf(inn + r * hn);
  const float ho = (1.f - z) * n + z * hf[idx];
  hf[idx] = ho;
  if (wout) wout[(size_t)(mb + m) * H_N + j] = ho;
}

// Single-direction, single-segment word-level GRU. 128 blocks; block owns 8
// h-columns (24 Whh rows bf16 in LDS). h carried across launches in hb (fp32).
__global__ __launch_bounds__(256)
void seq_kernel(const void* __restrict__ Whh, const void* __restrict__ bhh,
                const float* __restrict__ gi, float* hb, unsigned* cnt,
                float* __restrict__ ctx, const u32* __restrict__ flags,
                int wfi, int bfi, int word_base, int rev, int dirofs) {
  const u32 wm = flags[wfi], bm = flags[bfi];
  const int blk = blockIdx.x;               // 0..127
  const int tid = threadIdx.x;
  const int wave = tid >> 6, lane = tid & 63;
  const int j0 = blk * 8;

  __shared__ __align__(16) u16 wsh[24 * 1024];   // 48KB bf16 weights
  __shared__ float hshf[1024];                   // h_prev fp32
  __shared__ float ghs[24];
  __shared__ float bhs[24];
  __shared__ float hnew[8];

  for (int e = tid * 8; e < 24 * 1024; e += 256 * 8) {
    const int lr = e >> 10, col = e & 1023;
    const int g = lr >> 3, jj = lr & 7;
    *(short8*)&wsh[e] = ld8(Whh, (size_t)(g * 1024 + j0 + jj) * 1024 + col, wm);
  }
  if (tid < 24) bhs[tid] = ld1(bhh, (tid >> 3) * 1024 + j0 + (tid & 7), bm);
  __syncthreads();

  unsigned target = 0;
  for (int t = 0; t < SEG; ++t) {
    const int row = rev ? (SEG - 1 - t) : t;
    const int wt = word_base + row;
    // ---- all-gather h_prev (fp32 bits via u32 agent atomics) ----
    const u32* hsrc = (const u32*)(hb + (t & 1) * 1024);
    u32* hdst = (u32*)hshf;
    if (wave == 0) {
#pragma unroll
      for (int c = 0; c < 16; ++c)
        hdst[c * 64 + lane] = __hip_atomic_load(hsrc + c * 64 + lane,
                                                __ATOMIC_RELAXED, __HIP_MEMORY_SCOPE_AGENT);
    }
    __syncthreads();
    // per-lane h: pairs k = 2*(c*64+lane), +1
    float hreg[16];
#pragma unroll
    for (int c = 0; c < 8; ++c) {
      const int kp = 2 * (c * 64 + lane);
      hreg[2 * c]     = hshf[kp];
      hreg[2 * c + 1] = hshf[kp + 1];
    }
    // ---- matvec: 6 rows/wave; weights bf16-paired, h fp32 ----
#pragma unroll
    for (int q = 0; q < 6; ++q) {
      const int lr = wave * 6 + q;
      const u32* wrow = (const u32*)&wsh[lr * 1024];
      float s = 0.f;
#pragma unroll
      for (int c = 0; c < 8; ++c) {
        const u32 u = wrow[c * 64 + lane];
        union { u32 i; float f; } lo, hi;
        lo.i = u << 16; hi.i = u & 0xffff0000u;
        s = fmaf(lo.f, hreg[2 * c], s);
        s = fmaf(hi.f, hreg[2 * c + 1], s);
      }
#pragma unroll
      for (int off = 32; off > 0; off >>= 1) s += __shfl_xor(s, off);
      if (lane == 0) ghs[lr] = s;
    }
    __syncthreads();
    // ---- gates + outputs (8 columns) ----
    if (tid < 8) {
      const int jj = tid;
      const float hr = ghs[jj] + bhs[jj];
      const float hz = ghs[8 + jj] + bhs[8 + jj];
      const float hn = ghs[16 + jj] + bhs[16 + jj];
      const float* gim = gi + (size_t)row * G3_N + (j0 + jj);
      const float ir = gim[0], iz = gim[1024], inn = gim[2048];
      const float r = 1.f / (1.f + expf(-(ir + hr)));
      const float z = 1.f / (1.f + expf(-(iz + hz)));
      const float n = tanhf(inn + r * hn);
      const float hp = hshf[j0 + jj];
      const float ho = (1.f - z) * n + z * hp;
      ctx[(size_t)wt * 2048 + dirofs + j0 + jj] = ho;
      hnew[jj] = ho;
    }
    __syncthreads();
    if (tid < 8) {
      union { float f; u32 i; } v; v.f = hnew[tid];
      __hip_atomic_store((u32*)(hb + ((t + 1) & 1) * 1024) + blk * 8 + tid, v.i,
                         __ATOMIC_RELAXED, __HIP_MEMORY_SCOPE_AGENT);
    }
    target += 128;
    if (tid == 0) {
      __hip_atomic_fetch_add(cnt, 1u, __ATOMIC_RELEASE, __HIP_MEMORY_SCOPE_AGENT);
      while (__hip_atomic_load(cnt, __ATOMIC_ACQUIRE, __HIP_MEMORY_SCOPE_AGENT) < target)
        __builtin_amdgcn_s_sleep(2);
    }
    __syncthreads();
  }
}

extern "C" void kernel_launch(void* const* d_in, const int* in_sizes, int n_in,
                              void* d_out, int out_size, void* d_ws, size_t ws_size,
                              hipStream_t stream) {
  char* w = (char*)d_ws;
  // control block: flags [0,64) | cnts [64,1024) | hbuf fp32 [1024,17408)
  u32* flags = (u32*)(w);
  float* hbuf = (float*)(w + 1024);                 // 2 dirs x 2 bufs x 1024 fp32
  const size_t GBASE = 20480;
  float* G0  = (float*)(w + GBASE);                 // SEG*3072 fp32 = 6.29 MB
  float* GIc = G0;                                  // phase-1: CH*3072 fp32
  float* GHc = G0 + (size_t)CH * G3_N;
  float* HF  = (float*)(w + GBASE + (size_t)SEG * G3_N * 4);   // CH*1024 fp32

  hipMemsetAsync(w, 0, GBASE, stream);              // flags/cnts/hbuf

  sniffx_kernel<<<1, 64, 0, stream>>>((const int*)d_in[0], flags + 0);
  for (int i = 1; i <= 13; ++i)
    sniff_kernel<<<1, 64, 0, stream>>>((const u16*)d_in[i], flags + i);

  float* wemb = (float*)d_out;                      // word_emb fp32 [0 : 2M)
  float* ctx  = (float*)d_out + (size_t)W_N * H_N;  // ctx fp32 [2M : 6M)

  dim3 bb(16, 16);
  // ---- phase 1: char-GRU, 8 independent word-chunks of 256 ----
  dim3 gg1(G3_N / 32, CH / 32);
  for (int ch = 0; ch < W_N / CH; ++ch) {
    const int mb = ch * CH;
    hipMemsetAsync(HF, 0, (size_t)CH * H_N * 4, stream);   // h0 = 0
    for (int c = 0; c < C_N; ++c) {
      ngemm_kernel<1><<<gg1, bb, 0, stream>>>(d_in[1], d_in[2], d_in[4], GIc,
                                              d_in[0], c, C_N, E_N, flags, 1, 2, 4, mb);
      ngemm_kernel<0><<<gg1, bb, 0, stream>>>(HF, d_in[3], d_in[5], GHc,
                                              nullptr, 0, 0, H_N, flags, -2, 3, 5, 0);
      gru_cell_kernel<<<(CH * H_N) / 256, 256, 0, stream>>>(
          GIc, GHc, HF, (c == C_N - 1) ? wemb : (float*)nullptr, mb);
    }
  }

  // ---- phase 2: word-level bidirectional GRU, 4 segments of 512 per dir ----
  dim3 gg2(G3_N / 32, SEG / 32);
  for (int s = 0; s < W_N / SEG; ++s) {            // forward
    ngemm_kernel<0><<<gg2, bb, 0, stream>>>(wemb, d_in[6], d_in[8], G0,
                                            nullptr, 0, 0, H_N, flags, -2, 6, 8, s * SEG);
    seq_kernel<<<128, 256, 0, stream>>>(d_in[7], d_in[9], G0, hbuf,
                                        (unsigned*)(w + 64 + (0 * 4 + s) * 64),
                                        ctx, flags, 7, 9, s * SEG, 0, 0);
  }
  for (int s = W_N / SEG - 1; s >= 0; --s) {       // backward
    ngemm_kernel<0><<<gg2, bb, 0, stream>>>(wemb, d_in[10], d_in[12], G0,
                                            nullptr, 0, 0, H_N, flags, -2, 10, 12, s * SEG);
    seq_kernel<<<128, 256, 0, stream>>>(d_in[11], d_in[13], G0, hbuf + 2048,
                                        (unsigned*)(w + 64 + (1 * 4 + s) * 64),
                                        ctx, flags, 11, 13, s * SEG, 1, 1024);
  }
}